// Round 21
// baseline (139.662 us; speedup 1.0000x reference)
//
#include <hip/hip_runtime.h>
#include <math.h>

#define BB 32
#define DD 256
#define KK 2048
#define HW 1024
#define CHW (DD*HW)
#define NN (BB*HW)         // 32768 rows
#define BETA 0.25f
#define RROWS 32
#define NCAND 8
#define BIAS 0.125f

typedef __attribute__((ext_vector_type(8))) short short8v;   // 8 bf16 (4 VGPR)
typedef __attribute__((ext_vector_type(4))) float f32x4;

typedef const __attribute__((address_space(1))) void gv_t;
typedef __attribute__((address_space(3))) void lv_t;

__device__ __forceinline__ void gl_lds16(const void* g, void* l) {
    // LDS dest = wave-uniform base (+ lane*16 by HW); global src = per-lane addr
    __builtin_amdgcn_global_load_lds((gv_t*)g, (lv_t*)l, 16, 0, 0);
}

__device__ __forceinline__ unsigned bfr(float f) {           // fp32 -> bf16 RNE
    unsigned u = __float_as_uint(f);
    return (u + 0x7FFFu + ((u >> 16) & 1u)) >> 16;
}
__device__ __forceinline__ unsigned bfpack(float lo, float hi) {
    return bfr(lo) | (bfr(hi) << 16);
}

#define BARRIER() do { asm volatile("" ::: "memory"); \
                       __builtin_amdgcn_s_barrier();  \
                       asm volatile("" ::: "memory"); } while (0)

// ---- prep (r18-FROZEN): blocks 0..255 convert E->bf16, 32-code tiles;
//      blocks 256..767: one wave per code computes np-pairwise C bitwise. ----
__global__ __launch_bounds__(256) void k_prep(const float* __restrict__ E,
                                              uint4* __restrict__ EbfT,
                                              float* __restrict__ Cref,
                                              float* __restrict__ Ckey) {
    int bid = blockIdx.x;
    if (bid < 256) {
        int u = bid * 256 + threadIdx.x;                 // 0..65535
        int code = u & 31, kc = (u >> 5) & 3, c = (u >> 7) & 7, t = u >> 10;
        int k = t * 32 + code;
        const float* s = E + ((size_t)k * DD + c * 32 + kc * 8);
        float4 f0 = *reinterpret_cast<const float4*>(s);
        float4 f1 = *reinterpret_cast<const float4*>(s + 4);
        uint4 o;
        o.x = bfpack(f0.x, f0.y); o.y = bfpack(f0.z, f0.w);
        o.z = bfpack(f1.x, f1.y); o.w = bfpack(f1.z, f1.w);
        EbfT[u] = o;
    } else {
        const int w = threadIdx.x >> 6;                  // 4 waves/block
        const int lane = threadIdx.x & 63;
        const int k = (bid - 256) * 4 + w;               // one code per wave
        float racc = 0.0f;
        if (lane < 16) {
#pragma clang fp contract(off)
            const int j = lane & 7, h = lane >> 3;
            const float* e = E + (size_t)k * DD + h * 128 + j;
            for (int i = 0; i < 16; ++i) {
                float t = e[i * 8];
                racc += t * t;                           // mul then add, seq
            }
        }
        float v0 = __shfl(racc, 0, 64),  v1 = __shfl(racc, 1, 64);
        float v2 = __shfl(racc, 2, 64),  v3 = __shfl(racc, 3, 64);
        float v4 = __shfl(racc, 4, 64),  v5 = __shfl(racc, 5, 64);
        float v6 = __shfl(racc, 6, 64),  v7 = __shfl(racc, 7, 64);
        float v8 = __shfl(racc, 8, 64),  v9 = __shfl(racc, 9, 64);
        float va = __shfl(racc, 10, 64), vb = __shfl(racc, 11, 64);
        float vc = __shfl(racc, 12, 64), vd = __shfl(racc, 13, 64);
        float ve = __shfl(racc, 14, 64), vf = __shfl(racc, 15, 64);
        if (lane == 0) {
#pragma clang fp contract(off)
            float lo = ((v0 + v1) + (v2 + v3)) + ((v4 + v5) + (v6 + v7));
            float hi = ((v8 + v9) + (va + vb)) + ((vc + vd) + (ve + vf));
            float res = lo + hi;
            Cref[k] = res;
            Ckey[k] = res + BIAS;
        }
    }
}

// ---- MFMA screen v10c: r18's v10b with HARDENED sync — full vmcnt(0) drain
//      before the tile-ready barrier (only change vs the r18-passed file).
//      32-code tiles, LDS 36864 -> 4 blocks/CU, budget (512,4). ----
__global__ __launch_bounds__(512, 4) void k_screen(
        const float* __restrict__ X, const uint4* __restrict__ EbfT,
        const float* __restrict__ Ckey, uint2* __restrict__ ck)
{
    __shared__ __align__(1024) char lds[36864];   // 2x16KB E dbuf | 4KB ckl

    const int tid = threadIdx.x;
    const int w = tid >> 6;              // 0..7
    const int rg = w >> 1;               // 0..3 row group (16 rows each)
    const int cg = w & 1;                // 0..1 code group (16 codes each)
    const int lane = tid & 63;
    const int lid = lane & 15, kc = lane >> 4;
    const int bid = blockIdx.x;
    const int half = bid & 1;
    const int tbase = half * 32;         // 32-code tiles, 32 per half
    const int nb = (bid >> 1) * 64;
    const int b = nb >> 10;              // 64 | 1024 -> single b per block
    const int hw0 = nb & 1023;

    float* ckl = (float*)(lds + 32768);

    float ckg0 = Ckey[half * 1024 + tid];
    float ckg1 = Ckey[half * 1024 + 512 + tid];

    short8v a[8];                        // 16 rows x 256 d: 32 VGPR
    {
        const float* xb = X + (size_t)b * CHW + (hw0 + rg * 16 + lid);
        #pragma unroll
        for (int c = 0; c < 8; ++c) {
            const float* pp = xb + (size_t)(c * 32 + kc * 8) * HW;
            float f[8];
            #pragma unroll
            for (int j = 0; j < 8; ++j) f[j] = pp[(size_t)j * HW];
            uint4 v;
            v.x = bfpack(f[0], f[1]); v.y = bfpack(f[2], f[3]);
            v.z = bfpack(f[4], f[5]); v.w = bfpack(f[6], f[7]);
            a[c] = *reinterpret_cast<short8v*>(&v);
        }
    }
    ckl[tid] = ckg0;
    ckl[tid + 512] = ckg1;

    auto stage = [&](int t, int p) {     // t local (0..31); 8 waves x 2 x 1KB
        const uint4* src = EbfT + ((size_t)(tbase + t) * 1024 + w * 128 + lane);
        char* dst = lds + p * 16384 + (w * 128) * 16;
        #pragma unroll
        for (int i = 0; i < 2; ++i)
            gl_lds16(src + i * 64, dst + i * 1024);
    };
    stage(0, 0);
    stage(1, 1);
    asm volatile("s_waitcnt vmcnt(0) lgkmcnt(0)" ::: "memory");   // HARDENED
    BARRIER();

    unsigned t1[4], t2[4];               // top-2 per g
    #pragma unroll
    for (int g = 0; g < 4; ++g) { t1[g] = 0xFFFFFFFFu; t2[g] = 0xFFFFFFFFu; }

    f32x4 acc = (f32x4){0.f, 0.f, 0.f, 0.f};

    int p = 0;
    float pck = 0.f;
    #pragma unroll 1
    for (int tt = 0; tt < 32; ++tt) {
        float ckv = ckl[tt * 32 + cg * 16 + lid];

        // selection for tile tt-1 (register-only, overlaps ds_read latency)
        if (tt > 0) {
            unsigned tg = (unsigned)(tt - 1);          // local tile, 5 bits
            #pragma unroll
            for (int g = 0; g < 4; ++g) {
                float s = fmaf(-2.0f, acc[g], pck);
                unsigned key = (__float_as_uint(s) & 0xFFFFFFE0u) | tg;
                unsigned o1 = t1[g];
                unsigned hi = key > o1 ? key : o1;
                t1[g] = key < o1 ? key : o1;
                t2[g] = hi < t2[g] ? hi : t2[g];
                acc[g] = 0.0f;
            }
        }
        pck = ckv;

        const short8v* Ev = reinterpret_cast<const short8v*>(lds + p * 16384);
        #pragma unroll
        for (int c = 0; c < 8; ++c) {
            short8v b0 = Ev[c * 128 + kc * 32 + cg * 16 + lid];
            acc = __builtin_amdgcn_mfma_f32_16x16x32_bf16(a[c], b0, acc, 0, 0, 0);
        }

        BARRIER();
        if (tt < 30) {
            stage(tt + 2, p);                        // refill buf p (2-deep)
        }
        asm volatile("s_waitcnt vmcnt(0)" ::: "memory");   // HARDENED drain
        BARRIER();
        p ^= 1;
    }
    {
        unsigned tg = 31u;
        #pragma unroll
        for (int g = 0; g < 4; ++g) {
            float s = fmaf(-2.0f, acc[g], pck);
            unsigned key = (__float_as_uint(s) & 0xFFFFFFE0u) | tg;
            unsigned o1 = t1[g];
            unsigned hi = key > o1 ? key : o1;
            t1[g] = key < o1 ? key : o1;
            t2[g] = hi < t2[g] ? hi : t2[g];
        }
    }

    // ---- merge: 32 slots/row x 2 keys -> top-4 of this half ----
    uint2* mb = reinterpret_cast<uint2*>(lds);            // [64 rows][32 slots] 16KB
    uint2* scr = reinterpret_cast<uint2*>(lds + 16384);   // [64][4][4] 8KB
    #pragma unroll
    for (int g = 0; g < 4; ++g) {
        int row = rg * 16 + kc * 4 + g;
        int slot = cg * 16 + lid;
        uint2 v; v.x = t1[g]; v.y = t2[g];
        mb[row * 32 + slot] = v;
    }
    BARRIER();
    if (tid < 256) {
        int row = tid >> 2, q = tid & 3;
        unsigned prev = 0; int prevj = -1;
        for (int i = 0; i < 4; ++i) {
            unsigned cur = 0xFFFFFFFFu; int curj = 0x7FFFFFFF;
            #pragma unroll
            for (int s = 0; s < 8; ++s) {
                int slot = q * 8 + ((s + tid) & 7);       // bank-spread rotation
                uint2 kv = mb[row * 32 + slot];
                int j0 = slot * 2;
                { unsigned k2=kv.x; int j=j0;   if ((k2>prev||(k2==prev&&j>prevj)) && (k2<cur||(k2==cur&&j<curj))) {cur=k2;curj=j;} }
                { unsigned k2=kv.y; int j=j0+1; if ((k2>prev||(k2==prev&&j>prevj)) && (k2<cur||(k2==cur&&j<curj))) {cur=k2;curj=j;} }
            }
            uint2 pr; pr.x = cur; pr.y = (unsigned)curj;
            scr[(row * 4 + q) * 4 + i] = pr;
            prev = cur; prevj = curj;
        }
    }
    BARRIER();
    if (tid < 64) {
        unsigned prev = 0; int prevj = -1;
        unsigned short codes[4];
        for (int i = 0; i < 4; ++i) {
            unsigned cur = 0xFFFFFFFFu; int curj = 0x7FFFFFFF;
            for (int m = 0; m < 16; ++m) {
                int mm = (m + tid) & 15;
                uint2 pr = scr[tid * 16 + mm];
                unsigned k2 = pr.x; int j = (int)pr.y;
                if ((k2>prev||(k2==prev&&j>prevj)) && (k2<cur||(k2==cur&&j<curj))) {cur=k2;curj=j;}
            }
            prev = cur; prevj = curj;
            // k = half*1024 + local_tile*32 + slot
            codes[i] = (unsigned short)(half * 1024 + (int)(cur & 31u) * 32 + ((curj >> 1) & 31));
        }
        uint2 o;
        o.x = (unsigned)codes[0] | ((unsigned)codes[1] << 16);
        o.y = (unsigned)codes[2] | ((unsigned)codes[3] << 16);
        ck[(size_t)(nb + tid) * 2 + half] = o;
    }
}

// ---- refine+out v6 (r18-PASSED file, byte-identical) ----
__global__ __launch_bounds__(512) void k_refineout(const float* __restrict__ X,
                                                   const float* __restrict__ E,
                                                   const float* __restrict__ Cref,
                                                   const uint2* __restrict__ ck,
                                                   float* __restrict__ idx_out_f,
                                                   float* __restrict__ out) {
    __shared__ float Xl[RROWS][DD + 4];
    __shared__ float El[RROWS][DD + 4];
    __shared__ int bk_l[RROWS];
    const int tid = threadIdx.x;
    const int n0 = blockIdx.x * RROWS;
    const int b = n0 >> 10;
    const int hw0 = n0 & 1023;
    const float* xbase = X + (size_t)b * CHW + hw0;
    #pragma unroll
    for (int it = 0; it < 16; ++it) {
        int idx = tid + it * 512;                 // 0..8191
        int d = idx >> 5, rr = idx & 31;          // 128B coalesced runs
        Xl[rr][d] = xbase[(size_t)d * HW + rr];
    }
    __syncthreads();
    const int r = tid >> 4, c = tid & 15;
    const int sub = c & 7;
    uint4 ck4 = reinterpret_cast<const uint4*>(ck)[n0 + r];   // 8 ushort codes
    const unsigned short* cs = reinterpret_cast<const unsigned short*>(&ck4);

    // ---- A = np-pairwise sum(x^2), wave-parallel bitwise emulation ----
    float A;
    {
        float racc;
        {
#pragma clang fp contract(off)
            const int j = c & 7, h = c >> 3;
            const float* xr = &Xl[r][h * 128 + j];
            racc = 0.0f;
            for (int i = 0; i < 16; ++i) {
                float t = xr[i * 8];
                racc += t * t;
            }
        }
        float w1 = __shfl_xor(racc, 1, 16);
        float s1, s2, s4;
        {
#pragma clang fp contract(off)
            s1 = racc + w1;
        }
        float w2 = __shfl_xor(s1, 2, 16);
        {
#pragma clang fp contract(off)
            s2 = s1 + w2;
        }
        float w4 = __shfl_xor(s2, 4, 16);
        {
#pragma clang fp contract(off)
            s4 = s2 + w4;                         // lo (h=0 lanes) / hi (h=1)
        }
        float w8 = __shfl_xor(s4, 8, 16);
        {
#pragma clang fp contract(off)
            A = s4 + w8;                          // lo + hi
        }
    }

    float bd = INFINITY; int bk = 0x7FFFFFFF;
    #pragma unroll
    for (int cc = 0; cc < 4; ++cc) {
        int k = cs[cc * 2 + (c >> 3)] & 2047;    // insurance: legit codes <=2047
        const float* er = E + (size_t)k * DD;
        double p = 0.0;                          // f64: order-free proxy
        #pragma unroll
        for (int m = 0; m < 8; ++m) {
            // COALESCED: 8-lane group covers one contiguous 128B line per m
            float4 ev = *reinterpret_cast<const float4*>(er + m * 32 + sub * 4);
            float4 xv = *reinterpret_cast<const float4*>(&Xl[r][m * 32 + sub * 4]);
            p += (double)xv.x*ev.x + (double)xv.y*ev.y
               + (double)xv.z*ev.z + (double)xv.w*ev.w;
        }
        p += __shfl_xor(p, 1, 64);
        p += __shfl_xor(p, 2, 64);
        p += __shfl_xor(p, 4, 64);
        float dist;
        {
#pragma clang fp contract(off)
            float M  = (float)p;
            float Bt = 2.0f * M;
            float T1 = A - Bt;
            dist = T1 + Cref[k];
        }
        if (dist < bd || (dist == bd && k < bk)) { bd = dist; bk = k; }
    }
    {   // combine the two 8-lane candidate groups
        float bd2 = __shfl_xor(bd, 8, 64);
        int   bk2 = __shfl_xor(bk, 8, 64);
        if (bd2 < bd || (bd2 == bd && bk2 < bk)) { bd = bd2; bk = bk2; }
    }
    if (c == 0) {
        bk_l[r] = bk;
        idx_out_f[n0 + r] = (float)bk;
    }
    __syncthreads();
    {   // stage winning E rows coalesced (256B runs per row)
        int kk = bk_l[r];
        const float* er = E + (size_t)kk * DD;
        #pragma unroll
        for (int m = 0; m < 4; ++m)
            *reinterpret_cast<float4*>(&El[r][m * 64 + c * 4]) =
                *reinterpret_cast<const float4*>(er + m * 64 + c * 4);
    }
    __syncthreads();
    {   // fused output: out[b][d][hw0+rr], rr-fastest -> 2x128B segs per store
        const int rr = tid & 31;
        const int d0 = tid >> 5;                 // 0..15
        float* ob = out + (size_t)b * CHW + hw0 + rr;
        #pragma unroll
        for (int it = 0; it < 16; ++it) {
            int d = d0 + it * 16;
            float x = Xl[rr][d];
            float qv = El[rr][d];
            ob[(size_t)d * HW] = x + BETA * (qv - x);
        }
    }
}

extern "C" void kernel_launch(void* const* d_in, const int* in_sizes, int n_in,
                              void* d_out, int out_size, void* d_ws, size_t ws_size,
                              hipStream_t stream) {
    const float* lat = (const float*)d_in[0];      // (32,256,32,32) fp32
    const float* emb = (const float*)d_in[1];      // (2048,256) fp32
    float* out   = (float*)d_out;                  // 8388608 floats (output 0)
    float* idx_f = out + (size_t)BB * DD * HW;     // 32768 floats (output 1)

    // EbfT scratch in d_out (read only by k_screen, which completes before
    // k_refineout writes out). Ckey/Cref/ck in d_ws (~530 KB).
    char*  ob   = (char*)d_out;
    uint4* EbfT = (uint4*)(ob);                    // 1 MB

    char* ws = (char*)d_ws;
    float* Ckey = (float*)(ws + 0);                // 8 KB
    float* Cref = (float*)(ws + 8192);             // 8 KB
    uint2* ck   = (uint2*)(ws + 16384);            // 512 KB (2 x ushort4 per row)

    k_prep      <<<768, 256, 0, stream>>>(emb, EbfT, Cref, Ckey);
    k_screen    <<<NN / 64 * 2, 512, 0, stream>>>(lat, EbfT, Ckey, ck);
    k_refineout <<<NN / RROWS, 512, 0, stream>>>(lat, emb, Cref, ck, idx_f, out);
}

// Round 22
// 134.287 us; speedup vs baseline: 1.0400x; 1.0400x over previous
//
#include <hip/hip_runtime.h>
#include <math.h>

#define BB 32
#define DD 256
#define KK 2048
#define HW 1024
#define CHW (DD*HW)
#define NN (BB*HW)         // 32768 rows
#define BETA 0.25f
#define RROWS 32
#define NCAND 8
#define BIAS 0.125f

typedef __attribute__((ext_vector_type(8))) short short8v;   // 8 bf16 (4 VGPR)
typedef __attribute__((ext_vector_type(4))) float f32x4;

typedef const __attribute__((address_space(1))) void gv_t;
typedef __attribute__((address_space(3))) void lv_t;

__device__ __forceinline__ void gl_lds16(const void* g, void* l) {
    // LDS dest = wave-uniform base (+ lane*16 by HW); global src = per-lane addr
    __builtin_amdgcn_global_load_lds((gv_t*)g, (lv_t*)l, 16, 0, 0);
}

__device__ __forceinline__ unsigned bfr(float f) {           // fp32 -> bf16 RNE
    unsigned u = __float_as_uint(f);
    return (u + 0x7FFFu + ((u >> 16) & 1u)) >> 16;
}
__device__ __forceinline__ unsigned bfpack(float lo, float hi) {
    return bfr(lo) | (bfr(hi) << 16);
}

#define BARRIER() do { asm volatile("" ::: "memory"); \
                       __builtin_amdgcn_s_barrier();  \
                       asm volatile("" ::: "memory"); } while (0)

// ---- prep (r21-FROZEN): blocks 0..255 convert E->bf16, 32-code tiles;
//      blocks 256..767: one wave per code computes np-pairwise C bitwise. ----
__global__ __launch_bounds__(256) void k_prep(const float* __restrict__ E,
                                              uint4* __restrict__ EbfT,
                                              float* __restrict__ Cref,
                                              float* __restrict__ Ckey) {
    int bid = blockIdx.x;
    if (bid < 256) {
        int u = bid * 256 + threadIdx.x;                 // 0..65535
        int code = u & 31, kc = (u >> 5) & 3, c = (u >> 7) & 7, t = u >> 10;
        int k = t * 32 + code;
        const float* s = E + ((size_t)k * DD + c * 32 + kc * 8);
        float4 f0 = *reinterpret_cast<const float4*>(s);
        float4 f1 = *reinterpret_cast<const float4*>(s + 4);
        uint4 o;
        o.x = bfpack(f0.x, f0.y); o.y = bfpack(f0.z, f0.w);
        o.z = bfpack(f1.x, f1.y); o.w = bfpack(f1.z, f1.w);
        EbfT[u] = o;
    } else {
        const int w = threadIdx.x >> 6;                  // 4 waves/block
        const int lane = threadIdx.x & 63;
        const int k = (bid - 256) * 4 + w;               // one code per wave
        float racc = 0.0f;
        if (lane < 16) {
#pragma clang fp contract(off)
            const int j = lane & 7, h = lane >> 3;
            const float* e = E + (size_t)k * DD + h * 128 + j;
            for (int i = 0; i < 16; ++i) {
                float t = e[i * 8];
                racc += t * t;                           // mul then add, seq
            }
        }
        float v0 = __shfl(racc, 0, 64),  v1 = __shfl(racc, 1, 64);
        float v2 = __shfl(racc, 2, 64),  v3 = __shfl(racc, 3, 64);
        float v4 = __shfl(racc, 4, 64),  v5 = __shfl(racc, 5, 64);
        float v6 = __shfl(racc, 6, 64),  v7 = __shfl(racc, 7, 64);
        float v8 = __shfl(racc, 8, 64),  v9 = __shfl(racc, 9, 64);
        float va = __shfl(racc, 10, 64), vb = __shfl(racc, 11, 64);
        float vc = __shfl(racc, 12, 64), vd = __shfl(racc, 13, 64);
        float ve = __shfl(racc, 14, 64), vf = __shfl(racc, 15, 64);
        if (lane == 0) {
#pragma clang fp contract(off)
            float lo = ((v0 + v1) + (v2 + v3)) + ((v4 + v5) + (v6 + v7));
            float hi = ((v8 + v9) + (va + vb)) + ((vc + vd) + (ve + vf));
            float res = lo + hi;
            Cref[k] = res;
            Ckey[k] = res + BIAS;
        }
    }
}

// ---- MFMA screen v10c (r21-FROZEN, replay-validated): hardened vmcnt(0)
//      drains; 32-code tiles, LDS 36864 -> 4 blocks/CU, budget (512,4). ----
__global__ __launch_bounds__(512, 4) void k_screen(
        const float* __restrict__ X, const uint4* __restrict__ EbfT,
        const float* __restrict__ Ckey, uint2* __restrict__ ck)
{
    __shared__ __align__(1024) char lds[36864];   // 2x16KB E dbuf | 4KB ckl

    const int tid = threadIdx.x;
    const int w = tid >> 6;              // 0..7
    const int rg = w >> 1;               // 0..3 row group (16 rows each)
    const int cg = w & 1;                // 0..1 code group (16 codes each)
    const int lane = tid & 63;
    const int lid = lane & 15, kc = lane >> 4;
    const int bid = blockIdx.x;
    const int half = bid & 1;
    const int tbase = half * 32;         // 32-code tiles, 32 per half
    const int nb = (bid >> 1) * 64;
    const int b = nb >> 10;              // 64 | 1024 -> single b per block
    const int hw0 = nb & 1023;

    float* ckl = (float*)(lds + 32768);

    float ckg0 = Ckey[half * 1024 + tid];
    float ckg1 = Ckey[half * 1024 + 512 + tid];

    short8v a[8];                        // 16 rows x 256 d: 32 VGPR
    {
        const float* xb = X + (size_t)b * CHW + (hw0 + rg * 16 + lid);
        #pragma unroll
        for (int c = 0; c < 8; ++c) {
            const float* pp = xb + (size_t)(c * 32 + kc * 8) * HW;
            float f[8];
            #pragma unroll
            for (int j = 0; j < 8; ++j) f[j] = pp[(size_t)j * HW];
            uint4 v;
            v.x = bfpack(f[0], f[1]); v.y = bfpack(f[2], f[3]);
            v.z = bfpack(f[4], f[5]); v.w = bfpack(f[6], f[7]);
            a[c] = *reinterpret_cast<short8v*>(&v);
        }
    }
    ckl[tid] = ckg0;
    ckl[tid + 512] = ckg1;

    auto stage = [&](int t, int p) {     // t local (0..31); 8 waves x 2 x 1KB
        const uint4* src = EbfT + ((size_t)(tbase + t) * 1024 + w * 128 + lane);
        char* dst = lds + p * 16384 + (w * 128) * 16;
        #pragma unroll
        for (int i = 0; i < 2; ++i)
            gl_lds16(src + i * 64, dst + i * 1024);
    };
    stage(0, 0);
    stage(1, 1);
    asm volatile("s_waitcnt vmcnt(0) lgkmcnt(0)" ::: "memory");   // HARDENED
    BARRIER();

    unsigned t1[4], t2[4];               // top-2 per g
    #pragma unroll
    for (int g = 0; g < 4; ++g) { t1[g] = 0xFFFFFFFFu; t2[g] = 0xFFFFFFFFu; }

    f32x4 acc = (f32x4){0.f, 0.f, 0.f, 0.f};

    int p = 0;
    float pck = 0.f;
    #pragma unroll 1
    for (int tt = 0; tt < 32; ++tt) {
        float ckv = ckl[tt * 32 + cg * 16 + lid];

        // selection for tile tt-1 (register-only, overlaps ds_read latency)
        if (tt > 0) {
            unsigned tg = (unsigned)(tt - 1);          // local tile, 5 bits
            #pragma unroll
            for (int g = 0; g < 4; ++g) {
                float s = fmaf(-2.0f, acc[g], pck);
                unsigned key = (__float_as_uint(s) & 0xFFFFFFE0u) | tg;
                unsigned o1 = t1[g];
                unsigned hi = key > o1 ? key : o1;
                t1[g] = key < o1 ? key : o1;
                t2[g] = hi < t2[g] ? hi : t2[g];
                acc[g] = 0.0f;
            }
        }
        pck = ckv;

        const short8v* Ev = reinterpret_cast<const short8v*>(lds + p * 16384);
        #pragma unroll
        for (int c = 0; c < 8; ++c) {
            short8v b0 = Ev[c * 128 + kc * 32 + cg * 16 + lid];
            acc = __builtin_amdgcn_mfma_f32_16x16x32_bf16(a[c], b0, acc, 0, 0, 0);
        }

        BARRIER();
        if (tt < 30) {
            stage(tt + 2, p);                        // refill buf p (2-deep)
        }
        asm volatile("s_waitcnt vmcnt(0)" ::: "memory");   // HARDENED drain
        BARRIER();
        p ^= 1;
    }
    {
        unsigned tg = 31u;
        #pragma unroll
        for (int g = 0; g < 4; ++g) {
            float s = fmaf(-2.0f, acc[g], pck);
            unsigned key = (__float_as_uint(s) & 0xFFFFFFE0u) | tg;
            unsigned o1 = t1[g];
            unsigned hi = key > o1 ? key : o1;
            t1[g] = key < o1 ? key : o1;
            t2[g] = hi < t2[g] ? hi : t2[g];
        }
    }

    // ---- merge: 32 slots/row x 2 keys -> top-4 of this half ----
    uint2* mb = reinterpret_cast<uint2*>(lds);            // [64 rows][32 slots] 16KB
    uint2* scr = reinterpret_cast<uint2*>(lds + 16384);   // [64][4][4] 8KB
    #pragma unroll
    for (int g = 0; g < 4; ++g) {
        int row = rg * 16 + kc * 4 + g;
        int slot = cg * 16 + lid;
        uint2 v; v.x = t1[g]; v.y = t2[g];
        mb[row * 32 + slot] = v;
    }
    BARRIER();
    if (tid < 256) {
        int row = tid >> 2, q = tid & 3;
        unsigned prev = 0; int prevj = -1;
        for (int i = 0; i < 4; ++i) {
            unsigned cur = 0xFFFFFFFFu; int curj = 0x7FFFFFFF;
            #pragma unroll
            for (int s = 0; s < 8; ++s) {
                int slot = q * 8 + ((s + tid) & 7);       // bank-spread rotation
                uint2 kv = mb[row * 32 + slot];
                int j0 = slot * 2;
                { unsigned k2=kv.x; int j=j0;   if ((k2>prev||(k2==prev&&j>prevj)) && (k2<cur||(k2==cur&&j<curj))) {cur=k2;curj=j;} }
                { unsigned k2=kv.y; int j=j0+1; if ((k2>prev||(k2==prev&&j>prevj)) && (k2<cur||(k2==cur&&j<curj))) {cur=k2;curj=j;} }
            }
            uint2 pr; pr.x = cur; pr.y = (unsigned)curj;
            scr[(row * 4 + q) * 4 + i] = pr;
            prev = cur; prevj = curj;
        }
    }
    BARRIER();
    if (tid < 64) {
        unsigned prev = 0; int prevj = -1;
        unsigned short codes[4];
        for (int i = 0; i < 4; ++i) {
            unsigned cur = 0xFFFFFFFFu; int curj = 0x7FFFFFFF;
            for (int m = 0; m < 16; ++m) {
                int mm = (m + tid) & 15;
                uint2 pr = scr[tid * 16 + mm];
                unsigned k2 = pr.x; int j = (int)pr.y;
                if ((k2>prev||(k2==prev&&j>prevj)) && (k2<cur||(k2==cur&&j<curj))) {cur=k2;curj=j;}
            }
            prev = cur; prevj = curj;
            // k = half*1024 + local_tile*32 + slot
            codes[i] = (unsigned short)(half * 1024 + (int)(cur & 31u) * 32 + ((curj >> 1) & 31));
        }
        uint2 o;
        o.x = (unsigned)codes[0] | ((unsigned)codes[1] << 16);
        o.y = (unsigned)codes[2] | ((unsigned)codes[3] << 16);
        ck[(size_t)(nb + tid) * 2 + half] = o;
    }
}

// ---- refine (r20 code, first-validation-proven): 512 thr, 32 rows,
//      LDS = Xl only (33 KB -> 4 blocks/CU). Writes ind + idx floats. ----
__global__ __launch_bounds__(512) void k_refine(const float* __restrict__ X,
                                                const float* __restrict__ E,
                                                const float* __restrict__ Cref,
                                                const uint2* __restrict__ ck,
                                                float* __restrict__ idx_out_f,
                                                int* __restrict__ ind) {
    __shared__ float Xl[RROWS][DD + 4];
    const int tid = threadIdx.x;
    const int n0 = blockIdx.x * RROWS;
    const int b = n0 >> 10;
    const int hw0 = n0 & 1023;
    const float* xbase = X + (size_t)b * CHW + hw0;
    #pragma unroll
    for (int it = 0; it < 16; ++it) {
        int idx = tid + it * 512;                 // 0..8191
        int d = idx >> 5, rr = idx & 31;          // 128B coalesced runs
        Xl[rr][d] = xbase[(size_t)d * HW + rr];
    }
    __syncthreads();
    const int r = tid >> 4, c = tid & 15;
    const int sub = c & 7;
    uint4 ck4 = reinterpret_cast<const uint4*>(ck)[n0 + r];   // 8 ushort codes
    const unsigned short* cs = reinterpret_cast<const unsigned short*>(&ck4);

    // ---- A = np-pairwise sum(x^2), wave-parallel bitwise emulation ----
    float A;
    {
        float racc;
        {
#pragma clang fp contract(off)
            const int j = c & 7, h = c >> 3;
            const float* xr = &Xl[r][h * 128 + j];
            racc = 0.0f;
            for (int i = 0; i < 16; ++i) {
                float t = xr[i * 8];
                racc += t * t;
            }
        }
        float w1 = __shfl_xor(racc, 1, 16);
        float s1, s2, s4;
        {
#pragma clang fp contract(off)
            s1 = racc + w1;
        }
        float w2 = __shfl_xor(s1, 2, 16);
        {
#pragma clang fp contract(off)
            s2 = s1 + w2;
        }
        float w4 = __shfl_xor(s2, 4, 16);
        {
#pragma clang fp contract(off)
            s4 = s2 + w4;                         // lo (h=0 lanes) / hi (h=1)
        }
        float w8 = __shfl_xor(s4, 8, 16);
        {
#pragma clang fp contract(off)
            A = s4 + w8;                          // lo + hi
        }
    }

    float bd = INFINITY; int bk = 0x7FFFFFFF;
    #pragma unroll
    for (int cc = 0; cc < 4; ++cc) {
        int k = cs[cc * 2 + (c >> 3)] & 2047;    // insurance: legit codes <=2047
        const float* er = E + (size_t)k * DD;
        double p = 0.0;                          // f64: order-free proxy
        #pragma unroll
        for (int m = 0; m < 8; ++m) {
            // COALESCED: 8-lane group covers one contiguous 128B line per m
            float4 ev = *reinterpret_cast<const float4*>(er + m * 32 + sub * 4);
            float4 xv = *reinterpret_cast<const float4*>(&Xl[r][m * 32 + sub * 4]);
            p += (double)xv.x*ev.x + (double)xv.y*ev.y
               + (double)xv.z*ev.z + (double)xv.w*ev.w;
        }
        p += __shfl_xor(p, 1, 64);
        p += __shfl_xor(p, 2, 64);
        p += __shfl_xor(p, 4, 64);
        float dist;
        {
#pragma clang fp contract(off)
            float M  = (float)p;
            float Bt = 2.0f * M;
            float T1 = A - Bt;
            dist = T1 + Cref[k];
        }
        if (dist < bd || (dist == bd && k < bk)) { bd = dist; bk = k; }
    }
    {   // combine the two 8-lane candidate groups
        float bd2 = __shfl_xor(bd, 8, 64);
        int   bk2 = __shfl_xor(bk, 8, 64);
        if (bd2 < bd || (bd2 == bd && bk2 < bk)) { bd = bd2; bk = bk2; }
    }
    if (c == 0) {
        ind[n0 + r] = bk;
        idx_out_f[n0 + r] = (float)bk;
    }
}

// ---- out = x + BETA*(E[ind] - x), NCHW, fully-coalesced float4 (r11-proven) ----
__global__ __launch_bounds__(256) void k_out(const float* __restrict__ X,
                                             const float* __restrict__ E,
                                             const int* __restrict__ ind,
                                             float* __restrict__ out) {
    int gid = blockIdx.x * 256 + threadIdx.x;
    int e0 = gid << 2;
    int hw = e0 & 1023;
    int d  = (e0 >> 10) & 255;
    int b  = e0 >> 18;
    int n0 = (b << 10) | hw;

    float4 x = *reinterpret_cast<const float4*>(X + e0);
    int4  iv = *reinterpret_cast<const int4*>(ind + n0);
    float q0 = E[(size_t)iv.x * DD + d];
    float q1 = E[(size_t)iv.y * DD + d];
    float q2 = E[(size_t)iv.z * DD + d];
    float q3 = E[(size_t)iv.w * DD + d];
    float4 r;
    r.x = x.x + BETA * (q0 - x.x);
    r.y = x.y + BETA * (q1 - x.y);
    r.z = x.z + BETA * (q2 - x.z);
    r.w = x.w + BETA * (q3 - x.w);
    *reinterpret_cast<float4*>(out + e0) = r;
}

extern "C" void kernel_launch(void* const* d_in, const int* in_sizes, int n_in,
                              void* d_out, int out_size, void* d_ws, size_t ws_size,
                              hipStream_t stream) {
    const float* lat = (const float*)d_in[0];      // (32,256,32,32) fp32
    const float* emb = (const float*)d_in[1];      // (2048,256) fp32
    float* out   = (float*)d_out;                  // 8388608 floats (output 0)
    float* idx_f = out + (size_t)BB * DD * HW;     // 32768 floats (output 1)

    // EbfT scratch in d_out (read only by k_screen; k_out overwrites at end).
    // Ckey/Cref/ck/ind in d_ws (672 KB, r11/r12-proven footprint).
    char*  ob   = (char*)d_out;
    uint4* EbfT = (uint4*)(ob);                    // 1 MB

    char* ws = (char*)d_ws;
    float* Ckey = (float*)(ws + 0);                // 8 KB
    float* Cref = (float*)(ws + 8192);             // 8 KB
    uint2* ck   = (uint2*)(ws + 16384);            // 512 KB (2 x ushort4 per row)
    int*   ind  = (int*)(ws + 540672);             // 128 KB

    k_prep   <<<768, 256, 0, stream>>>(emb, EbfT, Cref, Ckey);
    k_screen <<<NN / 64 * 2, 512, 0, stream>>>(lat, EbfT, Ckey, ck);
    k_refine <<<NN / RROWS, 512, 0, stream>>>(lat, emb, Cref, ck, idx_f, ind);
    k_out    <<<(BB * DD * HW) / 4 / 256, 256, 0, stream>>>(lat, emb, ind, out);
}

// Round 24
// 112.549 us; speedup vs baseline: 1.2409x; 1.1931x over previous
//
#include <hip/hip_runtime.h>
#include <math.h>

#define BB 32
#define DD 256
#define KK 2048
#define HW 1024
#define CHW (DD*HW)
#define NN (BB*HW)         // 32768 rows
#define BETA 0.25f
#define RROWS 32
#define NCAND 8
#define BIAS 0.125f

typedef __attribute__((ext_vector_type(8))) short short8v;   // 8 bf16 (4 VGPR)
typedef __attribute__((ext_vector_type(4))) float f32x4;

typedef const __attribute__((address_space(1))) void gv_t;
typedef __attribute__((address_space(3))) void lv_t;

__device__ __forceinline__ void gl_lds16(const void* g, void* l) {
    // LDS dest = wave-uniform base (+ lane*16 by HW); global src = per-lane addr
    __builtin_amdgcn_global_load_lds((gv_t*)g, (lv_t*)l, 16, 0, 0);
}

__device__ __forceinline__ unsigned bfr(float f) {           // fp32 -> bf16 RNE
    unsigned u = __float_as_uint(f);
    return (u + 0x7FFFu + ((u >> 16) & 1u)) >> 16;
}
__device__ __forceinline__ unsigned bfpack(float lo, float hi) {
    return bfr(lo) | (bfr(hi) << 16);
}

#define BARRIER() do { asm volatile("" ::: "memory"); \
                       __builtin_amdgcn_s_barrier();  \
                       asm volatile("" ::: "memory"); } while (0)

// ---- prep (r21-FROZEN): blocks 0..255 convert E->bf16, 32-code tiles;
//      blocks 256..767: one wave per code computes np-pairwise C bitwise. ----
__global__ __launch_bounds__(256) void k_prep(const float* __restrict__ E,
                                              uint4* __restrict__ EbfT,
                                              float* __restrict__ Cref,
                                              float* __restrict__ Ckey) {
    int bid = blockIdx.x;
    if (bid < 256) {
        int u = bid * 256 + threadIdx.x;                 // 0..65535
        int code = u & 31, kc = (u >> 5) & 3, c = (u >> 7) & 7, t = u >> 10;
        int k = t * 32 + code;
        const float* s = E + ((size_t)k * DD + c * 32 + kc * 8);
        float4 f0 = *reinterpret_cast<const float4*>(s);
        float4 f1 = *reinterpret_cast<const float4*>(s + 4);
        uint4 o;
        o.x = bfpack(f0.x, f0.y); o.y = bfpack(f0.z, f0.w);
        o.z = bfpack(f1.x, f1.y); o.w = bfpack(f1.z, f1.w);
        EbfT[u] = o;
    } else {
        const int w = threadIdx.x >> 6;                  // 4 waves/block
        const int lane = threadIdx.x & 63;
        const int k = (bid - 256) * 4 + w;               // one code per wave
        float racc = 0.0f;
        if (lane < 16) {
#pragma clang fp contract(off)
            const int j = lane & 7, h = lane >> 3;
            const float* e = E + (size_t)k * DD + h * 128 + j;
            for (int i = 0; i < 16; ++i) {
                float t = e[i * 8];
                racc += t * t;                           // mul then add, seq
            }
        }
        float v0 = __shfl(racc, 0, 64),  v1 = __shfl(racc, 1, 64);
        float v2 = __shfl(racc, 2, 64),  v3 = __shfl(racc, 3, 64);
        float v4 = __shfl(racc, 4, 64),  v5 = __shfl(racc, 5, 64);
        float v6 = __shfl(racc, 6, 64),  v7 = __shfl(racc, 7, 64);
        float v8 = __shfl(racc, 8, 64),  v9 = __shfl(racc, 9, 64);
        float va = __shfl(racc, 10, 64), vb = __shfl(racc, 11, 64);
        float vc = __shfl(racc, 12, 64), vd = __shfl(racc, 13, 64);
        float ve = __shfl(racc, 14, 64), vf = __shfl(racc, 15, 64);
        if (lane == 0) {
#pragma clang fp contract(off)
            float lo = ((v0 + v1) + (v2 + v3)) + ((v4 + v5) + (v6 + v7));
            float hi = ((v8 + v9) + (va + vb)) + ((vc + vd) + (ve + vf));
            float res = lo + hi;
            Cref[k] = res;
            Ckey[k] = res + BIAS;
        }
    }
}

// ---- MFMA screen v10c (r21/r22-FROZEN, replay-validated): hardened vmcnt(0)
//      drains; 32-code tiles, LDS 36864 -> 4 blocks/CU, budget (512,4). ----
__global__ __launch_bounds__(512, 4) void k_screen(
        const float* __restrict__ X, const uint4* __restrict__ EbfT,
        const float* __restrict__ Ckey, uint2* __restrict__ ck)
{
    __shared__ __align__(1024) char lds[36864];   // 2x16KB E dbuf | 4KB ckl

    const int tid = threadIdx.x;
    const int w = tid >> 6;              // 0..7
    const int rg = w >> 1;               // 0..3 row group (16 rows each)
    const int cg = w & 1;                // 0..1 code group (16 codes each)
    const int lane = tid & 63;
    const int lid = lane & 15, kc = lane >> 4;
    const int bid = blockIdx.x;
    const int half = bid & 1;
    const int tbase = half * 32;         // 32-code tiles, 32 per half
    const int nb = (bid >> 1) * 64;
    const int b = nb >> 10;              // 64 | 1024 -> single b per block
    const int hw0 = nb & 1023;

    float* ckl = (float*)(lds + 32768);

    float ckg0 = Ckey[half * 1024 + tid];
    float ckg1 = Ckey[half * 1024 + 512 + tid];

    short8v a[8];                        // 16 rows x 256 d: 32 VGPR
    {
        const float* xb = X + (size_t)b * CHW + (hw0 + rg * 16 + lid);
        #pragma unroll
        for (int c = 0; c < 8; ++c) {
            const float* pp = xb + (size_t)(c * 32 + kc * 8) * HW;
            float f[8];
            #pragma unroll
            for (int j = 0; j < 8; ++j) f[j] = pp[(size_t)j * HW];
            uint4 v;
            v.x = bfpack(f[0], f[1]); v.y = bfpack(f[2], f[3]);
            v.z = bfpack(f[4], f[5]); v.w = bfpack(f[6], f[7]);
            a[c] = *reinterpret_cast<short8v*>(&v);
        }
    }
    ckl[tid] = ckg0;
    ckl[tid + 512] = ckg1;

    auto stage = [&](int t, int p) {     // t local (0..31); 8 waves x 2 x 1KB
        const uint4* src = EbfT + ((size_t)(tbase + t) * 1024 + w * 128 + lane);
        char* dst = lds + p * 16384 + (w * 128) * 16;
        #pragma unroll
        for (int i = 0; i < 2; ++i)
            gl_lds16(src + i * 64, dst + i * 1024);
    };
    stage(0, 0);
    stage(1, 1);
    asm volatile("s_waitcnt vmcnt(0) lgkmcnt(0)" ::: "memory");   // HARDENED
    BARRIER();

    unsigned t1[4], t2[4];               // top-2 per g
    #pragma unroll
    for (int g = 0; g < 4; ++g) { t1[g] = 0xFFFFFFFFu; t2[g] = 0xFFFFFFFFu; }

    f32x4 acc = (f32x4){0.f, 0.f, 0.f, 0.f};

    int p = 0;
    float pck = 0.f;
    #pragma unroll 1
    for (int tt = 0; tt < 32; ++tt) {
        float ckv = ckl[tt * 32 + cg * 16 + lid];

        // selection for tile tt-1 (register-only, overlaps ds_read latency)
        if (tt > 0) {
            unsigned tg = (unsigned)(tt - 1);          // local tile, 5 bits
            #pragma unroll
            for (int g = 0; g < 4; ++g) {
                float s = fmaf(-2.0f, acc[g], pck);
                unsigned key = (__float_as_uint(s) & 0xFFFFFFE0u) | tg;
                unsigned o1 = t1[g];
                unsigned hi = key > o1 ? key : o1;
                t1[g] = key < o1 ? key : o1;
                t2[g] = hi < t2[g] ? hi : t2[g];
                acc[g] = 0.0f;
            }
        }
        pck = ckv;

        const short8v* Ev = reinterpret_cast<const short8v*>(lds + p * 16384);
        #pragma unroll
        for (int c = 0; c < 8; ++c) {
            short8v b0 = Ev[c * 128 + kc * 32 + cg * 16 + lid];
            acc = __builtin_amdgcn_mfma_f32_16x16x32_bf16(a[c], b0, acc, 0, 0, 0);
        }

        BARRIER();
        if (tt < 30) {
            stage(tt + 2, p);                        // refill buf p (2-deep)
        }
        asm volatile("s_waitcnt vmcnt(0)" ::: "memory");   // HARDENED drain
        BARRIER();
        p ^= 1;
    }
    {
        unsigned tg = 31u;
        #pragma unroll
        for (int g = 0; g < 4; ++g) {
            float s = fmaf(-2.0f, acc[g], pck);
            unsigned key = (__float_as_uint(s) & 0xFFFFFFE0u) | tg;
            unsigned o1 = t1[g];
            unsigned hi = key > o1 ? key : o1;
            t1[g] = key < o1 ? key : o1;
            t2[g] = hi < t2[g] ? hi : t2[g];
        }
    }

    // ---- merge: 32 slots/row x 2 keys -> top-4 of this half ----
    uint2* mb = reinterpret_cast<uint2*>(lds);            // [64 rows][32 slots] 16KB
    uint2* scr = reinterpret_cast<uint2*>(lds + 16384);   // [64][4][4] 8KB
    #pragma unroll
    for (int g = 0; g < 4; ++g) {
        int row = rg * 16 + kc * 4 + g;
        int slot = cg * 16 + lid;
        uint2 v; v.x = t1[g]; v.y = t2[g];
        mb[row * 32 + slot] = v;
    }
    BARRIER();
    if (tid < 256) {
        int row = tid >> 2, q = tid & 3;
        unsigned prev = 0; int prevj = -1;
        for (int i = 0; i < 4; ++i) {
            unsigned cur = 0xFFFFFFFFu; int curj = 0x7FFFFFFF;
            #pragma unroll
            for (int s = 0; s < 8; ++s) {
                int slot = q * 8 + ((s + tid) & 7);       // bank-spread rotation
                uint2 kv = mb[row * 32 + slot];
                int j0 = slot * 2;
                { unsigned k2=kv.x; int j=j0;   if ((k2>prev||(k2==prev&&j>prevj)) && (k2<cur||(k2==cur&&j<curj))) {cur=k2;curj=j;} }
                { unsigned k2=kv.y; int j=j0+1; if ((k2>prev||(k2==prev&&j>prevj)) && (k2<cur||(k2==cur&&j<curj))) {cur=k2;curj=j;} }
            }
            uint2 pr; pr.x = cur; pr.y = (unsigned)curj;
            scr[(row * 4 + q) * 4 + i] = pr;
            prev = cur; prevj = curj;
        }
    }
    BARRIER();
    if (tid < 64) {
        unsigned prev = 0; int prevj = -1;
        unsigned short codes[4];
        for (int i = 0; i < 4; ++i) {
            unsigned cur = 0xFFFFFFFFu; int curj = 0x7FFFFFFF;
            for (int m = 0; m < 16; ++m) {
                int mm = (m + tid) & 15;
                uint2 pr = scr[tid * 16 + mm];
                unsigned k2 = pr.x; int j = (int)pr.y;
                if ((k2>prev||(k2==prev&&j>prevj)) && (k2<cur||(k2==cur&&j<curj))) {cur=k2;curj=j;}
            }
            prev = cur; prevj = curj;
            // k = half*1024 + local_tile*32 + slot
            codes[i] = (unsigned short)(half * 1024 + (int)(cur & 31u) * 32 + ((curj >> 1) & 31));
        }
        uint2 o;
        o.x = (unsigned)codes[0] | ((unsigned)codes[1] << 16);
        o.y = (unsigned)codes[2] | ((unsigned)codes[3] << 16);
        ck[(size_t)(nb + tid) * 2 + half] = o;
    }
}

// ---- refine (r22-FROZEN): 512 thr, 32 rows, LDS = Xl only (4 blocks/CU). ----
__global__ __launch_bounds__(512) void k_refine(const float* __restrict__ X,
                                                const float* __restrict__ E,
                                                const float* __restrict__ Cref,
                                                const uint2* __restrict__ ck,
                                                float* __restrict__ idx_out_f,
                                                int* __restrict__ ind) {
    __shared__ float Xl[RROWS][DD + 4];
    const int tid = threadIdx.x;
    const int n0 = blockIdx.x * RROWS;
    const int b = n0 >> 10;
    const int hw0 = n0 & 1023;
    const float* xbase = X + (size_t)b * CHW + hw0;
    #pragma unroll
    for (int it = 0; it < 16; ++it) {
        int idx = tid + it * 512;                 // 0..8191
        int d = idx >> 5, rr = idx & 31;          // 128B coalesced runs
        Xl[rr][d] = xbase[(size_t)d * HW + rr];
    }
    __syncthreads();
    const int r = tid >> 4, c = tid & 15;
    const int sub = c & 7;
    uint4 ck4 = reinterpret_cast<const uint4*>(ck)[n0 + r];   // 8 ushort codes
    const unsigned short* cs = reinterpret_cast<const unsigned short*>(&ck4);

    // ---- A = np-pairwise sum(x^2), wave-parallel bitwise emulation ----
    float A;
    {
        float racc;
        {
#pragma clang fp contract(off)
            const int j = c & 7, h = c >> 3;
            const float* xr = &Xl[r][h * 128 + j];
            racc = 0.0f;
            for (int i = 0; i < 16; ++i) {
                float t = xr[i * 8];
                racc += t * t;
            }
        }
        float w1 = __shfl_xor(racc, 1, 16);
        float s1, s2, s4;
        {
#pragma clang fp contract(off)
            s1 = racc + w1;
        }
        float w2 = __shfl_xor(s1, 2, 16);
        {
#pragma clang fp contract(off)
            s2 = s1 + w2;
        }
        float w4 = __shfl_xor(s2, 4, 16);
        {
#pragma clang fp contract(off)
            s4 = s2 + w4;                         // lo (h=0 lanes) / hi (h=1)
        }
        float w8 = __shfl_xor(s4, 8, 16);
        {
#pragma clang fp contract(off)
            A = s4 + w8;                          // lo + hi
        }
    }

    float bd = INFINITY; int bk = 0x7FFFFFFF;
    #pragma unroll
    for (int cc = 0; cc < 4; ++cc) {
        int k = cs[cc * 2 + (c >> 3)] & 2047;    // insurance: legit codes <=2047
        const float* er = E + (size_t)k * DD;
        double p = 0.0;                          // f64: order-free proxy
        #pragma unroll
        for (int m = 0; m < 8; ++m) {
            // COALESCED: 8-lane group covers one contiguous 128B line per m
            float4 ev = *reinterpret_cast<const float4*>(er + m * 32 + sub * 4);
            float4 xv = *reinterpret_cast<const float4*>(&Xl[r][m * 32 + sub * 4]);
            p += (double)xv.x*ev.x + (double)xv.y*ev.y
               + (double)xv.z*ev.z + (double)xv.w*ev.w;
        }
        p += __shfl_xor(p, 1, 64);
        p += __shfl_xor(p, 2, 64);
        p += __shfl_xor(p, 4, 64);
        float dist;
        {
#pragma clang fp contract(off)
            float M  = (float)p;
            float Bt = 2.0f * M;
            float T1 = A - Bt;
            dist = T1 + Cref[k];
        }
        if (dist < bd || (dist == bd && k < bk)) { bd = dist; bk = k; }
    }
    {   // combine the two 8-lane candidate groups
        float bd2 = __shfl_xor(bd, 8, 64);
        int   bk2 = __shfl_xor(bk, 8, 64);
        if (bd2 < bd || (bd2 == bd && bk2 < bk)) { bd = bd2; bk = bk2; }
    }
    if (c == 0) {
        ind[n0 + r] = bk;
        idx_out_f[n0 + r] = (float)bk;
    }
}

// ---- out v2b: LDS-transposed E staging (index-FIXED: 8 iters, 32 rows).
//      Stage: iter i reads E[ki[i]][tid] coalesced (1KB run) -> Elt[d][rr].
//      Out: u=0..2047 float4s: d=u>>3 (0..255), rr4=(u&7)*4 (0..28 < 36). ----
__global__ __launch_bounds__(256) void k_out(const float* __restrict__ X,
                                             const float* __restrict__ E,
                                             const int* __restrict__ ind,
                                             float* __restrict__ out) {
    __shared__ float Elt[DD][36];          // [d][rr], pitch 36 (16B-aligned)
    __shared__ int ki[32];
    const int tid = threadIdx.x;
    const int n0 = blockIdx.x * 32;
    const int b = n0 >> 10;
    const int hw0 = n0 & 1023;
    if (tid < 32) ki[tid] = ind[n0 + tid];
    __syncthreads();
    #pragma unroll 4
    for (int i = 0; i < 32; ++i) {         // stage row i: coalesced 1KB read
        Elt[tid][i] = E[(size_t)ki[i] * DD + tid];
    }
    __syncthreads();
    const float* xb = X + (size_t)b * CHW + hw0;
    float* ob = out + (size_t)b * CHW + hw0;
    #pragma unroll
    for (int i = 0; i < 8; ++i) {
        int u = tid + i * 256;             // 0..2047
        int d = u >> 3;                    // 0..255
        int rr4 = (u & 7) << 2;            // 0,4,..,28  (< 32 rows, < pitch 36)
        size_t off = (size_t)d * HW + rr4;
        float4 x = *reinterpret_cast<const float4*>(xb + off);
        float4 qv = *reinterpret_cast<const float4*>(&Elt[d][rr4]);
        float4 r;
        r.x = x.x + BETA * (qv.x - x.x);
        r.y = x.y + BETA * (qv.y - x.y);
        r.z = x.z + BETA * (qv.z - x.z);
        r.w = x.w + BETA * (qv.w - x.w);
        *reinterpret_cast<float4*>(ob + off) = r;
    }
}

extern "C" void kernel_launch(void* const* d_in, const int* in_sizes, int n_in,
                              void* d_out, int out_size, void* d_ws, size_t ws_size,
                              hipStream_t stream) {
    const float* lat = (const float*)d_in[0];      // (32,256,32,32) fp32
    const float* emb = (const float*)d_in[1];      // (2048,256) fp32
    float* out   = (float*)d_out;                  // 8388608 floats (output 0)
    float* idx_f = out + (size_t)BB * DD * HW;     // 32768 floats (output 1)

    // EbfT scratch in d_out (read only by k_screen; k_out overwrites at end).
    // Ckey/Cref/ck/ind in d_ws (672 KB, r11/r12-proven footprint).
    char*  ob   = (char*)d_out;
    uint4* EbfT = (uint4*)(ob);                    // 1 MB

    char* ws = (char*)d_ws;
    float* Ckey = (float*)(ws + 0);                // 8 KB
    float* Cref = (float*)(ws + 8192);             // 8 KB
    uint2* ck   = (uint2*)(ws + 16384);            // 512 KB (2 x ushort4 per row)
    int*   ind  = (int*)(ws + 540672);             // 128 KB

    k_prep   <<<768, 256, 0, stream>>>(emb, EbfT, Cref, Ckey);
    k_screen <<<NN / 64 * 2, 512, 0, stream>>>(lat, EbfT, Ckey, ck);
    k_refine <<<NN / RROWS, 512, 0, stream>>>(lat, emb, Cref, ck, idx_f, ind);
    k_out    <<<NN / 32, 256, 0, stream>>>(lat, emb, ind, out);
}